// Round 4
// baseline (180.566 us; speedup 1.0000x reference)
//
#include <hip/hip_runtime.h>

typedef unsigned short u16;
typedef __attribute__((ext_vector_type(8))) short bf16x8;   // 8 bf16 = 4 VGPR
typedef __attribute__((ext_vector_type(4))) float f32x4;
typedef __attribute__((ext_vector_type(8))) unsigned short u16x8;

#define DEVI static __device__ __forceinline__

constexpr int Bb = 8, Nn = 2048, Dd = 256;

DEVI u16 f2bf(float f) {
    unsigned int u = __builtin_bit_cast(unsigned int, f);
    u = (u + 0x7fffu + ((u >> 16) & 1u)) >> 16;   // RNE
    return (u16)u;
}
DEVI float bf2f(u16 v) {
    return __builtin_bit_cast(float, (unsigned int)v << 16);
}

// async global->LDS, 16B per lane; lds dest = wave-uniform base (+lane*16 by HW)
DEVI void gl_lds16(const void* g, void* l) {
    __builtin_amdgcn_global_load_lds(
        (const __attribute__((address_space(1))) unsigned int*)g,
        (__attribute__((address_space(3))) unsigned int*)l, 16, 0, 0);
}

// ---------------- prep: x -> bf16 xb + transposed xbt + row sum-of-squares --
__global__ __launch_bounds__(256) void prep_xt_kernel(
    const float* __restrict__ x, u16* __restrict__ xb, u16* __restrict__ xbt,
    float* __restrict__ sq) {
    int n0 = blockIdx.x * 64;
    int b = blockIdx.y;
    int t = threadIdx.x;
    __shared__ __align__(16) u16 tile[64 * 256];   // row stride 512B, swizzled
    int row = t >> 2;
    int c0 = (t & 3) * 64;
    const float* xr = x + ((size_t)(b * Nn + n0 + row)) * Dd + c0;
    u16* xbr = xb + ((size_t)(b * Nn + n0 + row)) * Dd + c0;
    float ss = 0.f;
#pragma unroll
    for (int cc = 0; cc < 16; ++cc) {
        float4 v = *(const float4*)(xr + cc * 4);
        ss += v.x * v.x + v.y * v.y + v.z * v.z + v.w * v.w;
        ushort4 o;
        o.x = f2bf(v.x); o.y = f2bf(v.y); o.z = f2bf(v.z); o.w = f2bf(v.w);
        *(ushort4*)(xbr + cc * 4) = o;
        int cb = (c0 + cc * 4) * 2;          // byte col offset (8B aligned)
        *(ushort4*)((char*)tile + row * 512 + (cb ^ ((row & 7) << 4))) = o;
    }
    ss += __shfl_xor(ss, 1);
    ss += __shfl_xor(ss, 2);
    if ((t & 3) == 0) sq[b * Nn + n0 + row] = ss;
    __syncthreads();
#pragma unroll
    for (int p = 0; p < 8; ++p) {
        int d = p * 32 + (t >> 3);
        int n8 = (t & 7) * 8;
        u16x8 vv;
#pragma unroll
        for (int e = 0; e < 8; ++e) {
            int r2 = n8 + e;
            vv[e] = *(const u16*)((char*)tile + r2 * 512 + ((d * 2) ^ ((r2 & 7) << 4)));
        }
        *(u16x8*)(xbt + ((size_t)(b * Dd + d)) * Nn + n0 + n8) = vv;
    }
}

// ---------------- prep: W -> bf16 ------------------------------------------
__global__ void prep_w_kernel(const float* __restrict__ W, u16* __restrict__ Wb) {
    int i = (blockIdx.x * 256 + threadIdx.x) * 4;
    const float4 v = *(const float4*)(W + i);
    ushort4 o;
    o.x = f2bf(v.x); o.y = f2bf(v.y); o.z = f2bf(v.z); o.w = f2bf(v.w);
    *(ushort4*)(Wb + i) = o;
}

// ---------------- fused: S^T = Xm.Xn^T, P = mean_h exp(-dist/denom), O += P.Xm
// 512 thr = 8 waves x 32 n-rows (BM=256); grid = 8 batches x 8 n-tiles x 4 m-quarters.
// Double-buffered LDS staging with counted vmcnt + raw barriers.
__global__ __launch_bounds__(512, 1) void fused_adj_kernel(
    const u16* __restrict__ xb, const u16* __restrict__ xbt,
    const float* __restrict__ sq, const float* __restrict__ lsig,
    u16* __restrict__ opart) {
    int bid = blockIdx.x;
    int b = bid & 7;                 // batch == XCD (all resident blocks share batch)
    int j = bid >> 3;
    int q = j & 3;                   // m-quarter
    int nt8 = j >> 2;                // n-tile within batch
    int r0 = b * Nn + nt8 * 256;     // first n-row (global)
    int m0b = b * Nn + q * 512;      // first m-row of quarter (global)
    int mq0 = q * 512;               // first m-col of quarter (within batch)

    int tid = threadIdx.x;
    int w = tid >> 6, l = tid & 63;
    int l15 = l & 15, lhi = l >> 4;

    // 160 KiB LDS: sXm A/B (32K each) | sXmt A/B (32K each) | sP 8 x 4K
    __shared__ __align__(16) char smem[163840];
    char* sXmA = smem;
    char* sXmB = smem + 32768;
    char* sXmtA = smem + 65536;
    char* sXmtB = smem + 98304;
    char* sP = smem + 131072 + w * 4096;

    float nc[4];
#pragma unroll
    for (int h = 0; h < 4; ++h) {
        float denom = 2.f * expf(2.f * lsig[h]) + 1e-6f;
        nc[h] = -1.44269504f / denom;
    }
    bool uniform = (lsig[0] == lsig[1]) && (lsig[1] == lsig[2]) && (lsig[2] == lsig[3]);

    // Xn B-fragments in registers: 2 row-groups x 8 k-tiles
    bf16x8 bf[2][8];
    float sqn[2];
#pragma unroll
    for (int rg = 0; rg < 2; ++rg) {
        const u16* xr = xb + (size_t)(r0 + w * 32 + rg * 16 + l15) * Dd;
#pragma unroll
        for (int kt = 0; kt < 8; ++kt) bf[rg][kt] = *(const bf16x8*)(xr + kt * 32 + lhi * 8);
        sqn[rg] = sq[r0 + w * 32 + rg * 16 + l15];
    }

    f32x4 of[2][16];
#pragma unroll
    for (int rg = 0; rg < 2; ++rg)
#pragma unroll
        for (int dt = 0; dt < 16; ++dt) of[rg][dt] = (f32x4){0.f, 0.f, 0.f, 0.f};

    int swz = (l15 & 7) << 4;        // read-side XOR for 16-row strided reads

// issue 8 global_load_lds for tile tt into (SXM, SXMT)
#define STAGE(SXM, SXMT, tt) {                                                \
    int m0_ = m0b + (tt) * 64;                                                \
    int mc0_ = mq0 + (tt) * 64;                                               \
    _Pragma("unroll") for (int it = 0; it < 4; ++it) {                        \
        int c0 = it * 512 + w * 64;                                           \
        int c = c0 + l;                                                       \
        int row = c >> 5, c16 = c & 31;                                       \
        gl_lds16(xb + (size_t)(m0_ + row) * Dd + (c16 ^ (row & 7)) * 8,       \
                 (SXM) + c0 * 16);                                            \
    }                                                                          \
    _Pragma("unroll") for (int it = 0; it < 4; ++it) {                        \
        int c0 = it * 512 + w * 64;                                           \
        int c = c0 + l;                                                       \
        int row = c >> 3, c16 = c & 7;                                        \
        gl_lds16(xbt + (size_t)(b * Dd + row) * Nn + mc0_ + (c16 ^ (row & 7)) * 8, \
                 (SXMT) + c0 * 16);                                           \
    } }

#define LOADSQ(SQV, tt) {                                                     \
    _Pragma("unroll") for (int mt = 0; mt < 4; ++mt)                          \
        SQV[mt] = *(const float4*)(sq + m0b + (tt) * 64 + mt * 16 + lhi * 4); \
    }

#define COMPUTE(SXM, SXMT, SQV) {                                             \
    _Pragma("unroll") for (int mt = 0; mt < 4; ++mt) {                        \
        f32x4 sfv0 = (f32x4){0.f, 0.f, 0.f, 0.f};                             \
        f32x4 sfv1 = (f32x4){0.f, 0.f, 0.f, 0.f};                             \
        _Pragma("unroll") for (int kt = 0; kt < 8; ++kt) {                    \
            bf16x8 av = *(const bf16x8*)((SXM) + (mt * 16 + l15) * 512 +      \
                                         ((kt * 64 + lhi * 16) ^ swz));       \
            sfv0 = __builtin_amdgcn_mfma_f32_16x16x32_bf16(av, bf[0][kt], sfv0, 0, 0, 0); \
            sfv1 = __builtin_amdgcn_mfma_f32_16x16x32_bf16(av, bf[1][kt], sfv1, 0, 0, 0); \
        }                                                                      \
        float sm[4] = {SQV[mt].x, SQV[mt].y, SQV[mt].z, SQV[mt].w};           \
        _Pragma("unroll") for (int rg = 0; rg < 2; ++rg) {                    \
            f32x4 sfv = rg ? sfv1 : sfv0;                                     \
            ushort4 pk;                                                       \
            _Pragma("unroll") for (int r = 0; r < 4; ++r) {                   \
                float d2 = fmaxf(fmaf(-2.f, sfv[r], sqn[rg] + sm[r]), 0.f);   \
                float p = exp2f(d2 * nc[0]);                                  \
                if (!uniform)                                                 \
                    p = 0.25f * (p + exp2f(d2 * nc[1]) + exp2f(d2 * nc[2]) + exp2f(d2 * nc[3])); \
                ((u16*)&pk)[r] = f2bf(p);                                     \
            }                                                                  \
            int n_ = rg * 16 + l15;                                           \
            *(ushort4*)(sP + n_ * 128 + ((mt * 32 + lhi * 8) ^ ((n_ & 7) << 4))) = pk; \
        }                                                                      \
    }                                                                          \
    _Pragma("unroll") for (int kt2 = 0; kt2 < 2; ++kt2) {                     \
        bf16x8 pa0 = *(const bf16x8*)(sP + l15 * 128 + ((kt2 * 64 + lhi * 16) ^ swz)); \
        bf16x8 pa1 = *(const bf16x8*)(sP + (16 + l15) * 128 + ((kt2 * 64 + lhi * 16) ^ swz)); \
        _Pragma("unroll") for (int dt = 0; dt < 16; ++dt) {                   \
            bf16x8 bv = *(const bf16x8*)((SXMT) + (dt * 16 + l15) * 128 +     \
                                         ((kt2 * 64 + lhi * 16) ^ swz));      \
            of[0][dt] = __builtin_amdgcn_mfma_f32_16x16x32_bf16(pa0, bv, of[0][dt], 0, 0, 0); \
            of[1][dt] = __builtin_amdgcn_mfma_f32_16x16x32_bf16(pa1, bv, of[1][dt], 0, 0, 0); \
        }                                                                      \
    } }

    float4 sqvA[4], sqvB[4];

    // prologue: tile 0 into A
    STAGE(sXmA, sXmtA, 0)
    LOADSQ(sqvA, 0)

    for (int tt = 0; tt < 4; ++tt) {
        int t0 = tt * 2;
        // --- compute t0 from A, stage t0+1 into B ---
        STAGE(sXmB, sXmtB, t0 + 1)
        LOADSQ(sqvB, t0 + 1)
        asm volatile("s_waitcnt vmcnt(12)" ::: "memory");
        __builtin_amdgcn_s_barrier();
        COMPUTE(sXmA, sXmtA, sqvA)
        __builtin_amdgcn_s_barrier();
        // --- compute t0+1 from B, stage t0+2 into A ---
        if (tt < 3) {
            STAGE(sXmA, sXmtA, t0 + 2)
            LOADSQ(sqvA, t0 + 2)
            asm volatile("s_waitcnt vmcnt(12)" ::: "memory");
        } else {
            asm volatile("s_waitcnt vmcnt(0)" ::: "memory");
        }
        __builtin_amdgcn_s_barrier();
        COMPUTE(sXmB, sXmtB, sqvB)
        __builtin_amdgcn_s_barrier();
    }

#undef STAGE
#undef LOADSQ
#undef COMPUTE

    // write bf16 partial for this m-quarter
    u16* od = opart + (size_t)q * ((size_t)Bb * Nn * Dd);
#pragma unroll
    for (int rg = 0; rg < 2; ++rg)
#pragma unroll
        for (int dt = 0; dt < 16; ++dt)
#pragma unroll
            for (int r = 0; r < 4; ++r) {
                size_t row = (size_t)(r0 + w * 32 + rg * 16 + lhi * 4 + r);
                od[row * Dd + dt * 16 + l15] = f2bf(of[rg][dt][r]);
            }
}

// ---------------- projection (sum(partials) @ W^T + b) + ELU + residual + LN
__global__ __launch_bounds__(512, 1) void proj_ln_kernel(
    const u16* __restrict__ opart, const u16* __restrict__ Wb,
    const u16* __restrict__ xbres, const float* __restrict__ bvec,
    const float* __restrict__ gamma, const float* __restrict__ beta,
    float* __restrict__ out) {
    int tid = threadIdx.x, w = tid >> 6, l = tid & 63;
    int rg = w & 3, h = w >> 2;
    int lrow = l & 15, lhi = l >> 4;
    size_t row0 = (size_t)blockIdx.x * 64 + rg * 16;
    const size_t QS = (size_t)Bb * Nn * Dd;

    __shared__ __align__(16) float xch[8 * 16 * 2 * 64];   // 64 KiB

    f32x4 acc[16];
#pragma unroll
    for (int jt = 0; jt < 16; ++jt) acc[jt] = (f32x4){0.f, 0.f, 0.f, 0.f};

#pragma unroll
    for (int kk = 0; kk < 4; ++kk) {
        int kc = h * 4 + kk;
        float as[8] = {0.f, 0.f, 0.f, 0.f, 0.f, 0.f, 0.f, 0.f};
#pragma unroll
        for (int qq = 0; qq < 4; ++qq) {
            u16x8 v = *(const u16x8*)(opart + QS * qq + (row0 + lrow) * Dd + kc * 32 + lhi * 8);
#pragma unroll
            for (int e = 0; e < 8; ++e) as[e] += bf2f(v[e]);
        }
        bf16x8 a;
#pragma unroll
        for (int e = 0; e < 8; ++e) a[e] = (short)f2bf(as[e]);
#pragma unroll
        for (int jt = 0; jt < 16; ++jt) {
            bf16x8 bv = *(const bf16x8*)(Wb + (size_t)(jt * 16 + lrow) * Dd + kc * 32 + lhi * 8);
            acc[jt] = __builtin_amdgcn_mfma_f32_16x16x32_bf16(a, bv, acc[jt], 0, 0, 0);
        }
    }

    // exchange: write my OTHER-half r values; partner (w^4) wrote my half
#pragma unroll
    for (int jt = 0; jt < 16; ++jt)
#pragma unroll
        for (int qq = 0; qq < 2; ++qq) {
            int r = (1 - h) * 2 + qq;
            xch[(w * 16 + jt) * 128 + qq * 64 + l] = acc[jt][r];
        }
    __syncthreads();
#pragma unroll
    for (int jt = 0; jt < 16; ++jt)
#pragma unroll
        for (int qq = 0; qq < 2; ++qq)
            acc[jt][h * 2 + qq] += xch[((w ^ 4) * 16 + jt) * 128 + qq * 64 + l];

#pragma unroll
    for (int qq = 0; qq < 2; ++qq) {
        int r = h * 2 + qq;
        size_t grow = row0 + lhi * 4 + r;
        float vbuf[16];
        float s1 = 0.f, s2 = 0.f;
#pragma unroll
        for (int jt = 0; jt < 16; ++jt) {
            int jcol = jt * 16 + lrow;
            float v = acc[jt][r] + bvec[jcol];
            float e = v > 0.f ? v : (exp2f(v * 1.44269504f) - 1.f);   // ELU
            float res = e + bf2f(xbres[grow * Dd + jcol]);
            vbuf[jt] = res;
            s1 += res;
            s2 += res * res;
        }
#pragma unroll
        for (int m = 1; m < 16; m <<= 1) {
            s1 += __shfl_xor(s1, m);
            s2 += __shfl_xor(s2, m);
        }
        float mean = s1 * (1.f / 256.f);
        float var = s2 * (1.f / 256.f) - mean * mean;
        float rstd = rsqrtf(var + 1e-5f);
#pragma unroll
        for (int jt = 0; jt < 16; ++jt) {
            int jcol = jt * 16 + lrow;
            out[grow * Dd + jcol] = (vbuf[jt] - mean) * rstd * gamma[jcol] + beta[jcol];
        }
    }
}

// ---------------------------------------------------------------------------
extern "C" void kernel_launch(void* const* d_in, const int* in_sizes, int n_in,
                              void* d_out, int out_size, void* d_ws, size_t ws_size,
                              hipStream_t stream) {
    const float* x = (const float*)d_in[0];
    const float* lsig = (const float*)d_in[1];
    const float* W = (const float*)d_in[2];
    const float* bvec = (const float*)d_in[3];
    const float* gamma = (const float*)d_in[4];
    const float* beta = (const float*)d_in[5];
    float* out = (float*)d_out;

    char* ws = (char*)d_ws;
    u16* xb = (u16*)ws;                                   // 8 MiB
    u16* xbt = (u16*)(ws + 8388608);                      // 8 MiB
    float* sq = (float*)(ws + 16777216);                  // 64 KiB
    u16* Wb = (u16*)(ws + 16842752);                      // 128 KiB
    u16* opart = (u16*)(ws + 16973824);                   // 4 x 8 MiB bf16 partials

    prep_xt_kernel<<<dim3(Nn / 64, Bb), dim3(256), 0, stream>>>(x, xb, xbt, sq);
    prep_w_kernel<<<dim3(64), dim3(256), 0, stream>>>(W, Wb);
    fused_adj_kernel<<<dim3(256), dim3(512), 0, stream>>>(xb, xbt, sq, lsig, opart);
    proj_ln_kernel<<<dim3(Bb * Nn / 64), dim3(512), 0, stream>>>(opart, Wb, xb, bvec, gamma, beta, out);
}

// Round 5
// 116.027 us; speedup vs baseline: 1.5562x; 1.5562x over previous
//
#include <hip/hip_runtime.h>

typedef unsigned short u16;
typedef __attribute__((ext_vector_type(8))) short bf16x8;   // 8 bf16 = 4 VGPR
typedef __attribute__((ext_vector_type(4))) float f32x4;
typedef __attribute__((ext_vector_type(8))) unsigned short u16x8;

#define DEVI static __device__ __forceinline__

constexpr int Bb = 8, Nn = 2048, Dd = 256;

DEVI u16 f2bf(float f) {
    unsigned int u = __builtin_bit_cast(unsigned int, f);
    u = (u + 0x7fffu + ((u >> 16) & 1u)) >> 16;   // RNE
    return (u16)u;
}
DEVI float bf2f(u16 v) {
    return __builtin_bit_cast(float, (unsigned int)v << 16);
}

// async global->LDS, 16B per lane; lds dest = wave-uniform base (+lane*16 by HW)
DEVI void gl_lds16(const void* g, void* l) {
    __builtin_amdgcn_global_load_lds(
        (const __attribute__((address_space(1))) unsigned int*)g,
        (__attribute__((address_space(3))) unsigned int*)l, 16, 0, 0);
}

// ---------------- prep: x -> bf16 xb + transposed xbt + row sum-of-squares --
__global__ __launch_bounds__(256) void prep_xt_kernel(
    const float* __restrict__ x, u16* __restrict__ xb, u16* __restrict__ xbt,
    float* __restrict__ sq) {
    int n0 = blockIdx.x * 64;
    int b = blockIdx.y;
    int t = threadIdx.x;
    __shared__ __align__(16) u16 tile[64 * 256];   // row stride 512B, swizzled
    int row = t >> 2;
    int c0 = (t & 3) * 64;
    const float* xr = x + ((size_t)(b * Nn + n0 + row)) * Dd + c0;
    u16* xbr = xb + ((size_t)(b * Nn + n0 + row)) * Dd + c0;
    float ss = 0.f;
#pragma unroll
    for (int cc = 0; cc < 16; ++cc) {
        float4 v = *(const float4*)(xr + cc * 4);
        ss += v.x * v.x + v.y * v.y + v.z * v.z + v.w * v.w;
        ushort4 o;
        o.x = f2bf(v.x); o.y = f2bf(v.y); o.z = f2bf(v.z); o.w = f2bf(v.w);
        *(ushort4*)(xbr + cc * 4) = o;
        int cb = (c0 + cc * 4) * 2;          // byte col offset (8B aligned)
        *(ushort4*)((char*)tile + row * 512 + (cb ^ ((row & 7) << 4))) = o;
    }
    ss += __shfl_xor(ss, 1);
    ss += __shfl_xor(ss, 2);
    if ((t & 3) == 0) sq[b * Nn + n0 + row] = ss;
    __syncthreads();
#pragma unroll
    for (int p = 0; p < 8; ++p) {
        int d = p * 32 + (t >> 3);
        int n8 = (t & 7) * 8;
        u16x8 vv;
#pragma unroll
        for (int e = 0; e < 8; ++e) {
            int r2 = n8 + e;
            vv[e] = *(const u16*)((char*)tile + r2 * 512 + ((d * 2) ^ ((r2 & 7) << 4)));
        }
        *(u16x8*)(xbt + ((size_t)(b * Dd + d)) * Nn + n0 + n8) = vv;
    }
}

// ---------------- prep: W -> bf16 ------------------------------------------
__global__ void prep_w_kernel(const float* __restrict__ W, u16* __restrict__ Wb) {
    int i = (blockIdx.x * 256 + threadIdx.x) * 4;
    const float4 v = *(const float4*)(W + i);
    ushort4 o;
    o.x = f2bf(v.x); o.y = f2bf(v.y); o.z = f2bf(v.z); o.w = f2bf(v.w);
    *(ushort4*)(Wb + i) = o;
}

// ---------------- fused: S^T = Xm.Xn^T, P = mean_h exp(-dist/denom), O += P.Xm
// 256 thr = 4 waves x 64 n-rows (block: 256 n-rows); m-tile = 32, 16 dbuf steps.
// R_n = 4: every LDS A/B read feeds 4 MFMAs. Zero per-tile VGPR pipeline state.
__global__ __launch_bounds__(256, 1) void fused_adj_kernel(
    const u16* __restrict__ xb, const u16* __restrict__ xbt,
    const float* __restrict__ sq, const float* __restrict__ lsig,
    u16* __restrict__ opart) {
    int bid = blockIdx.x;
    int xcd = bid & 7, j = bid >> 3;
    int g = xcd + 8 * (j >> 3);      // 0..31  (4 (b,q) pairs per XCD)
    int nt8 = j & 7;                 // n-tile within batch
    int b = g >> 2, q = g & 3;
    int r0 = b * Nn + nt8 * 256;     // first n-row (global)
    int m0b = b * Nn + q * 512;      // first m-row of quarter (global)
    int mq0 = q * 512;               // first m-col of quarter (within batch)

    int tid = threadIdx.x;
    int w = tid >> 6, l = tid & 63;
    int l15 = l & 15, lhi = l >> 4;

    // LDS 84KB: XmA/B 16K each | XmtA/B 16K each | sP 4x4K | sq 2K
    __shared__ __align__(16) char smem[83968];
    char* sXmA = smem;
    char* sXmB = smem + 16384;
    char* sXmtA = smem + 32768;
    char* sXmtB = smem + 49152;
    char* sP = smem + 65536 + w * 4096;
    float* sq_lds = (float*)(smem + 81920);

    float nc[4];
#pragma unroll
    for (int h = 0; h < 4; ++h) {
        float denom = 2.f * expf(2.f * lsig[h]) + 1e-6f;
        nc[h] = -1.44269504f / denom;
    }
    bool uniform = (lsig[0] == lsig[1]) && (lsig[1] == lsig[2]) && (lsig[2] == lsig[3]);

    // quarter's m-side sq -> LDS (512 floats)
    {
        int i2 = tid * 2;
        float2 v = *(const float2*)(sq + m0b + i2);
        *(float2*)(sq_lds + i2) = v;
    }

    // Xn B-fragments in registers: 4 row-groups x 8 k-tiles (128 VGPR)
    bf16x8 bf[4][8];
    float sqn[4];
#pragma unroll
    for (int rg = 0; rg < 4; ++rg) {
        const u16* xr = xb + (size_t)(r0 + w * 64 + rg * 16 + l15) * Dd;
#pragma unroll
        for (int kt = 0; kt < 8; ++kt) bf[rg][kt] = *(const bf16x8*)(xr + kt * 32 + lhi * 8);
        sqn[rg] = sq[r0 + w * 64 + rg * 16 + l15];
    }

    f32x4 of[4][16];                 // 256 accums -> AGPR file
#pragma unroll
    for (int rg = 0; rg < 4; ++rg)
#pragma unroll
        for (int dt = 0; dt < 16; ++dt) of[rg][dt] = (f32x4){0.f, 0.f, 0.f, 0.f};

    int swz = (l15 & 7) << 4;        // read-side XOR for sXm 512B rows

// stage m-tile tt (32 rows): Xm 16KB + Xmt 16KB, 8 gl_lds16 per wave
#define STAGE(SXM, SXMT, tt) {                                                 \
    int m0_ = m0b + (tt) * 32;                                                 \
    int mc0_ = mq0 + (tt) * 32;                                                \
    _Pragma("unroll") for (int it = 0; it < 4; ++it) {                         \
        int c = w * 4 + it;                                                    \
        int row = c * 2 + (l >> 5);                                            \
        int col = l & 31;                                                      \
        gl_lds16(xb + (size_t)(m0_ + row) * Dd + (col ^ (row & 7)) * 8,        \
                 (SXM) + c * 1024);                                            \
    }                                                                           \
    _Pragma("unroll") for (int it = 0; it < 4; ++it) {                         \
        int c = w * 4 + it;                                                    \
        int drow = c * 16 + (l >> 2);                                          \
        gl_lds16(xbt + (size_t)(b * Dd + drow) * Nn + mc0_ + (l & 3) * 8,      \
                 (SXMT) + c * 1024);                                           \
    } }

#define COMPUTE(SXM, SXMT, tt) {                                               \
    _Pragma("unroll") for (int mt = 0; mt < 2; ++mt) {                         \
        float4 smv = *(const float4*)(sq_lds + (tt) * 32 + mt * 16 + lhi * 4); \
        f32x4 sfv[4];                                                          \
        _Pragma("unroll") for (int rg = 0; rg < 4; ++rg)                       \
            sfv[rg] = (f32x4){0.f, 0.f, 0.f, 0.f};                             \
        _Pragma("unroll") for (int kt = 0; kt < 8; ++kt) {                     \
            bf16x8 av = *(const bf16x8*)((SXM) + (mt * 16 + l15) * 512 +       \
                                         ((kt * 64 + lhi * 16) ^ swz));        \
            _Pragma("unroll") for (int rg = 0; rg < 4; ++rg)                   \
                sfv[rg] = __builtin_amdgcn_mfma_f32_16x16x32_bf16(             \
                    av, bf[rg][kt], sfv[rg], 0, 0, 0);                         \
        }                                                                       \
        float sm[4] = {smv.x, smv.y, smv.z, smv.w};                            \
        _Pragma("unroll") for (int rg = 0; rg < 4; ++rg) {                     \
            ushort4 pk;                                                        \
            _Pragma("unroll") for (int r = 0; r < 4; ++r) {                    \
                float d2 = fmaxf(fmaf(-2.f, sfv[rg][r], sqn[rg] + sm[r]), 0.f);\
                float p = exp2f(d2 * nc[0]);                                   \
                if (!uniform)                                                  \
                    p = 0.25f * (p + exp2f(d2 * nc[1]) + exp2f(d2 * nc[2]) +   \
                                 exp2f(d2 * nc[3]));                           \
                ((u16*)&pk)[r] = f2bf(p);                                      \
            }                                                                   \
            *(ushort4*)(sP + (rg * 16 + l15) * 64 + mt * 32 + lhi * 8) = pk;   \
        }                                                                       \
    }                                                                           \
    bf16x8 pa[4];                                                              \
    _Pragma("unroll") for (int rg = 0; rg < 4; ++rg)                           \
        pa[rg] = *(const bf16x8*)(sP + (rg * 16 + l15) * 64 + lhi * 16);       \
    _Pragma("unroll") for (int dt = 0; dt < 16; ++dt) {                        \
        bf16x8 bv = *(const bf16x8*)((SXMT) + (dt * 16 + l15) * 64 + lhi * 16);\
        _Pragma("unroll") for (int rg = 0; rg < 4; ++rg)                       \
            of[rg][dt] = __builtin_amdgcn_mfma_f32_16x16x32_bf16(              \
                pa[rg], bv, of[rg][dt], 0, 0, 0);                              \
    } }

    // prologue: tile 0 into A; __syncthreads drains everything once
    STAGE(sXmA, sXmtA, 0)
    __syncthreads();

    for (int tt = 0; tt < 8; ++tt) {
        int t0 = tt * 2;
        STAGE(sXmB, sXmtB, t0 + 1)
        asm volatile("s_waitcnt vmcnt(8)" ::: "memory");
        __builtin_amdgcn_s_barrier();
        COMPUTE(sXmA, sXmtA, t0)
        __builtin_amdgcn_s_barrier();
        if (tt < 7) {
            STAGE(sXmA, sXmtA, t0 + 2)
            asm volatile("s_waitcnt vmcnt(8)" ::: "memory");
        } else {
            asm volatile("s_waitcnt vmcnt(0)" ::: "memory");
        }
        __builtin_amdgcn_s_barrier();
        COMPUTE(sXmB, sXmtB, t0 + 1)
        __builtin_amdgcn_s_barrier();
    }

#undef STAGE
#undef COMPUTE

    // write bf16 partial for this m-quarter
    u16* od = opart + (size_t)q * ((size_t)Bb * Nn * Dd);
#pragma unroll
    for (int rg = 0; rg < 4; ++rg)
#pragma unroll
        for (int dt = 0; dt < 16; ++dt)
#pragma unroll
            for (int r = 0; r < 4; ++r) {
                size_t row = (size_t)(r0 + w * 64 + rg * 16 + lhi * 4 + r);
                od[row * Dd + dt * 16 + l15] = f2bf(of[rg][dt][r]);
            }
}

// ---------------- projection (sum(partials) @ W^T + b) + ELU + residual + LN
__global__ __launch_bounds__(512, 1) void proj_ln_kernel(
    const u16* __restrict__ opart, const u16* __restrict__ Wb,
    const u16* __restrict__ xbres, const float* __restrict__ bvec,
    const float* __restrict__ gamma, const float* __restrict__ beta,
    float* __restrict__ out) {
    int tid = threadIdx.x, w = tid >> 6, l = tid & 63;
    int rg = w & 3, h = w >> 2;
    int lrow = l & 15, lhi = l >> 4;
    size_t row0 = (size_t)blockIdx.x * 64 + rg * 16;
    const size_t QS = (size_t)Bb * Nn * Dd;

    __shared__ __align__(16) float xch[8 * 16 * 2 * 64];   // 64 KiB

    f32x4 acc[16];
#pragma unroll
    for (int jt = 0; jt < 16; ++jt) acc[jt] = (f32x4){0.f, 0.f, 0.f, 0.f};

#pragma unroll
    for (int kk = 0; kk < 4; ++kk) {
        int kc = h * 4 + kk;
        float as[8] = {0.f, 0.f, 0.f, 0.f, 0.f, 0.f, 0.f, 0.f};
#pragma unroll
        for (int qq = 0; qq < 4; ++qq) {
            u16x8 v = *(const u16x8*)(opart + QS * qq + (row0 + lrow) * Dd + kc * 32 + lhi * 8);
#pragma unroll
            for (int e = 0; e < 8; ++e) as[e] += bf2f(v[e]);
        }
        bf16x8 a;
#pragma unroll
        for (int e = 0; e < 8; ++e) a[e] = (short)f2bf(as[e]);
#pragma unroll
        for (int jt = 0; jt < 16; ++jt) {
            bf16x8 bv = *(const bf16x8*)(Wb + (size_t)(jt * 16 + lrow) * Dd + kc * 32 + lhi * 8);
            acc[jt] = __builtin_amdgcn_mfma_f32_16x16x32_bf16(a, bv, acc[jt], 0, 0, 0);
        }
    }

    // exchange: write my OTHER-half r values; partner (w^4) wrote my half
#pragma unroll
    for (int jt = 0; jt < 16; ++jt)
#pragma unroll
        for (int qq = 0; qq < 2; ++qq) {
            int r = (1 - h) * 2 + qq;
            xch[(w * 16 + jt) * 128 + qq * 64 + l] = acc[jt][r];
        }
    __syncthreads();
#pragma unroll
    for (int jt = 0; jt < 16; ++jt)
#pragma unroll
        for (int qq = 0; qq < 2; ++qq)
            acc[jt][h * 2 + qq] += xch[((w ^ 4) * 16 + jt) * 128 + qq * 64 + l];

#pragma unroll
    for (int qq = 0; qq < 2; ++qq) {
        int r = h * 2 + qq;
        size_t grow = row0 + lhi * 4 + r;
        float vbuf[16];
        float s1 = 0.f, s2 = 0.f;
#pragma unroll
        for (int jt = 0; jt < 16; ++jt) {
            int jcol = jt * 16 + lrow;
            float v = acc[jt][r] + bvec[jcol];
            float e = v > 0.f ? v : (exp2f(v * 1.44269504f) - 1.f);   // ELU
            float res = e + bf2f(xbres[grow * Dd + jcol]);
            vbuf[jt] = res;
            s1 += res;
            s2 += res * res;
        }
#pragma unroll
        for (int m = 1; m < 16; m <<= 1) {
            s1 += __shfl_xor(s1, m);
            s2 += __shfl_xor(s2, m);
        }
        float mean = s1 * (1.f / 256.f);
        float var = s2 * (1.f / 256.f) - mean * mean;
        float rstd = rsqrtf(var + 1e-5f);
#pragma unroll
        for (int jt = 0; jt < 16; ++jt) {
            int jcol = jt * 16 + lrow;
            out[grow * Dd + jcol] = (vbuf[jt] - mean) * rstd * gamma[jcol] + beta[jcol];
        }
    }
}

// ---------------------------------------------------------------------------
extern "C" void kernel_launch(void* const* d_in, const int* in_sizes, int n_in,
                              void* d_out, int out_size, void* d_ws, size_t ws_size,
                              hipStream_t stream) {
    const float* x = (const float*)d_in[0];
    const float* lsig = (const float*)d_in[1];
    const float* W = (const float*)d_in[2];
    const float* bvec = (const float*)d_in[3];
    const float* gamma = (const float*)d_in[4];
    const float* beta = (const float*)d_in[5];
    float* out = (float*)d_out;

    char* ws = (char*)d_ws;
    u16* xb = (u16*)ws;                                   // 8 MiB
    u16* xbt = (u16*)(ws + 8388608);                      // 8 MiB
    float* sq = (float*)(ws + 16777216);                  // 64 KiB
    u16* Wb = (u16*)(ws + 16842752);                      // 128 KiB
    u16* opart = (u16*)(ws + 16973824);                   // 4 x 8 MiB bf16 partials

    prep_xt_kernel<<<dim3(Nn / 64, Bb), dim3(256), 0, stream>>>(x, xb, xbt, sq);
    prep_w_kernel<<<dim3(64), dim3(256), 0, stream>>>(W, Wb);
    fused_adj_kernel<<<dim3(256), dim3(256), 0, stream>>>(xb, xbt, sq, lsig, opart);
    proj_ln_kernel<<<dim3(Bb * Nn / 64), dim3(512), 0, stream>>>(opart, Wb, xb, bvec, gamma, beta, out);
}